// Round 4
// baseline (26.759 us; speedup 1.0000x reference)
//
#include <hip/hip_runtime.h>
#include <cmath>

#define NATOMS 16384
#define MNBR   32
#define ROW    33      // center + 32 neighbors
#define APS    2       // atoms per half-wave (sequential)
#define APB    16      // atoms per block: 4 waves x 2 sides x APS

__device__ __forceinline__ float sel3(int s, float v0, float v1, float v2) {
    float r = (s == 0) ? v0 : v1;
    return (s == 2) ? v2 : r;
}

__global__ __launch_bounds__(256) void sw_energy_kernel(
    const float* __restrict__ coords,
    const float* __restrict__ A_,    const float* __restrict__ B_,
    const float* __restrict__ p_,    const float* __restrict__ q_,
    const float* __restrict__ sigma_,const float* __restrict__ gamma_,
    const float* __restrict__ cutoff_,const float* __restrict__ lam_,
    const float* __restrict__ cb0_,  const float* __restrict__ cjk_,
    const int*   __restrict__ elements,
    const int*   __restrict__ nl,
    float* __restrict__ out)
{
    // wave-private compacted triplet candidates: [wave][side][slot]
    __shared__ float cdx[4][2][32], cdy[4][2][32], cdz[4][2][32];
    __shared__ float crr[4][2][32], chh[4][2][32];
    __shared__ float wsum[4];

    const int tid  = threadIdx.x;
    const int wave = tid >> 6;
    const int lane = tid & 63;
    const int side = lane >> 5;
    const int hl   = lane & 31;

    // uniform params -> scalar loads, no LDS, no barrier
    const float a0 = A_[0],     a1 = A_[1],     a2 = A_[2];
    const float b0 = B_[0],     b1 = B_[1],     b2 = B_[2];
    const float p0 = p_[0],     p1 = p_[1],     p2 = p_[2];
    const float q0 = q_[0],     q1 = q_[1],     q2 = q_[2];
    const float s0 = sigma_[0], s1 = sigma_[1], s2v = sigma_[2];
    const float g0 = gamma_[0], g1 = gamma_[1], g2 = gamma_[2];
    const float c0 = cutoff_[0],c1 = cutoff_[1],c2 = cutoff_[2];
    const float lam0 = lam_[0], lam1 = lam_[1];
    const float cb0v = cb0_[0], cb1v = cb0_[1];
    const float cjk0 = cjk_[0], cjk1 = cjk_[1];

    const unsigned long long halfmask = side ? 0xFFFFFFFF00000000ull : 0x00000000FFFFFFFFull;

    float acc = 0.0f;

    #pragma unroll
    for (int a = 0; a < APS; ++a) {
        const int atom = blockIdx.x * APB + wave * (2 * APS) + side * APS + a;
        const int base = atom * ROW;

        const int   ei  = elements[base];
        const int   ci  = nl[base];
        const float xix = coords[3*ci+0];
        const float xiy = coords[3*ci+1];
        const float xiz = coords[3*ci+2];

        // ---- pair term + triplet-candidate compaction ----
        const int   j  = nl[base + 1 + hl];
        const int   ej = elements[base + 1 + hl];
        const float dx = coords[3*j+0] - xix;
        const float dy = coords[3*j+1] - xiy;
        const float dz = coords[3*j+2] - xiz;
        const float r  = sqrtf(dx*dx + dy*dy + dz*dz);
        const int   s  = ei + ej;
        const float c  = sel3(s, c0, c1, c2);
        const bool  valid = (r < c);

        float h = 0.0f;
        if (valid) {
            const float sg     = sel3(s, s0, s1, s2v);
            const float inv_rc = 1.0f / (r - c);               // negative
            const float l2     = log2f(sg / r);
            const float e2     = sel3(s, a0, a1, a2)
                               * (sel3(s, b0, b1, b2) * exp2f(sel3(s, p0, p1, p2) * l2)
                                  - exp2f(sel3(s, q0, q1, q2) * l2))
                               * expf(sg * inv_rc);
            acc += 0.5f * e2;
            h = sel3(s, g0, g1, g2) * inv_rc;                  // gamma/(r - c)
        }

        // triplet participation: ej == 1-ei (=> ei!=ej & ej==ek automatic) and rij<cij
        const bool participate = valid && (ej != ei);
        const unsigned long long ballot = __ballot(participate);
        const int m = __popcll(ballot & halfmask);
        if (participate) {
            const int slot = __popcll(ballot & halfmask & ((1ull << lane) - 1ull));
            cdx[wave][side][slot] = dx;
            cdy[wave][side][slot] = dy;
            cdz[wave][side][slot] = dz;
            crr[wave][side][slot] = r;
            chh[wave][side][slot] = h;
        }
        // wave-private LDS, wave-lockstep: no barrier needed

        // ---- triplet term over compacted pairs (usually <= 1 iteration) ----
        const float lam_e = ei ? lam1 : lam0;
        const float cb_e  = ei ? cb1v : cb0v;
        const float cjk_e = ei ? cjk1 : cjk0;
        const float cjk2  = cjk_e * cjk_e;
        const int npairs  = (m * (m - 1)) >> 1;

        for (int t = hl; t < npairs; t += 32) {
            int kk = (int)(0.5f * (1.0f + sqrtf(8.0f * (float)t + 1.0f)));
            if (kk*(kk-1)/2 > t)          --kk;
            else if ((kk+1)*kk/2 <= t)    ++kk;
            const int jj = t - ((kk*(kk-1)) >> 1);

            const float dxv  = cdx[wave][side][kk] - cdx[wave][side][jj];
            const float dyv  = cdy[wave][side][kk] - cdy[wave][side][jj];
            const float dzv  = cdz[wave][side][kk] - cdz[wave][side][jj];
            const float rjk2 = dxv*dxv + dyv*dyv + dzv*dzv;
            if (rjk2 < cjk2) {
                const float rj   = crr[wave][side][jj];
                const float rk   = crr[wave][side][kk];
                const float cosb = (rj*rj + rk*rk - rjk2) * 0.5f / (rj * rk);
                const float dcb  = cosb - cb_e;
                acc += lam_e * expf(chh[wave][side][jj] + chh[wave][side][kk]) * dcb * dcb;
            }
        }
    }

    // ---- wave reduce (64 lanes) then block reduce, one atomic per block ----
    #pragma unroll
    for (int off = 32; off > 0; off >>= 1)
        acc += __shfl_xor(acc, off, 64);
    if (lane == 0) wsum[wave] = acc;
    __syncthreads();
    if (tid == 0)
        atomicAdd(out, wsum[0] + wsum[1] + wsum[2] + wsum[3]);
}

extern "C" void kernel_launch(void* const* d_in, const int* in_sizes, int n_in,
                              void* d_out, int out_size, void* d_ws, size_t ws_size,
                              hipStream_t stream)
{
    const float* coords  = (const float*)d_in[0];
    const float* A_      = (const float*)d_in[1];
    const float* B_      = (const float*)d_in[2];
    const float* p_      = (const float*)d_in[3];
    const float* q_      = (const float*)d_in[4];
    const float* sigma_  = (const float*)d_in[5];
    const float* gamma_  = (const float*)d_in[6];
    const float* cutoff_ = (const float*)d_in[7];
    const float* lam_    = (const float*)d_in[8];
    const float* cb0_    = (const float*)d_in[9];
    const float* cjk_    = (const float*)d_in[10];
    const int*   elements= (const int*)d_in[11];
    const int*   nl      = (const int*)d_in[12];

    float* out = (float*)d_out;

    hipMemsetAsync(out, 0, sizeof(float), stream);

    const int nblocks = NATOMS / APB;          // 1024
    sw_energy_kernel<<<nblocks, 256, 0, stream>>>(
        coords, A_, B_, p_, q_, sigma_, gamma_, cutoff_,
        lam_, cb0_, cjk_, elements, nl, out);
}

// Round 5
// 11.801 us; speedup vs baseline: 2.2675x; 2.2675x over previous
//
#include <hip/hip_runtime.h>
#include <cmath>

#define NATOMS 16384
#define MNBR   32
#define ROW    33      // center + 32 neighbors
#define NBLK   2048    // 8 atoms/block: 4 waves x 2 half-waves
#define NWAVESUM (NBLK * 4)

__device__ __forceinline__ float sel3(int s, float v0, float v1, float v2) {
    float r = (s == 0) ? v0 : v1;
    return (s == 2) ? v2 : r;
}

__global__ __launch_bounds__(256) void sw_energy_kernel(
    const float* __restrict__ coords,
    const float* __restrict__ A_,    const float* __restrict__ B_,
    const float* __restrict__ p_,    const float* __restrict__ q_,
    const float* __restrict__ sigma_,const float* __restrict__ gamma_,
    const float* __restrict__ cutoff_,const float* __restrict__ lam_,
    const float* __restrict__ cb0_,  const float* __restrict__ cjk_,
    const int*   __restrict__ elements,
    const int*   __restrict__ nl,
    float* __restrict__ wave_sums)
{
    // wave-private compacted triplet candidates: [wave][side][slot]
    __shared__ float4 cpos[4][2][32];   // {dx, dy, dz, r}
    __shared__ float  chh [4][2][32];   // gamma/(r-c)

    const int tid  = threadIdx.x;
    const int wave = tid >> 6;
    const int lane = tid & 63;
    const int side = lane >> 5;
    const int hl   = lane & 31;

    // uniform params -> scalar loads, no LDS, no barrier
    const float a0 = A_[0],     a1 = A_[1],     a2 = A_[2];
    const float b0 = B_[0],     b1 = B_[1],     b2 = B_[2];
    const float p0 = p_[0],     p1 = p_[1],     p2 = p_[2];
    const float q0 = q_[0],     q1 = q_[1],     q2 = q_[2];
    const float s0 = sigma_[0], s1 = sigma_[1], s2v = sigma_[2];
    const float g0 = gamma_[0], g1 = gamma_[1], g2 = gamma_[2];
    const float c0 = cutoff_[0],c1 = cutoff_[1],c2 = cutoff_[2];
    const float lam0 = lam_[0], lam1 = lam_[1];
    const float cb0v = cb0_[0], cb1v = cb0_[1];
    const float cjk0 = cjk_[0], cjk1 = cjk_[1];

    const int atom = (blockIdx.x << 3) + wave * 2 + side;   // grid exact
    const int base = atom * ROW;

    const int   ei  = elements[base];
    const int   ci  = nl[base];
    const float xix = coords[3*ci+0];
    const float xiy = coords[3*ci+1];
    const float xiz = coords[3*ci+2];

    float acc = 0.0f;

    // ---- pair term + triplet-candidate compaction (all 64 lanes busy) ----
    const int   j  = nl[base + 1 + hl];
    const int   ej = elements[base + 1 + hl];
    const float dx = coords[3*j+0] - xix;
    const float dy = coords[3*j+1] - xiy;
    const float dz = coords[3*j+2] - xiz;
    const float r  = __builtin_amdgcn_sqrtf(dx*dx + dy*dy + dz*dz);
    const int   s  = ei + ej;
    const float c  = sel3(s, c0, c1, c2);
    const bool  valid = (r < c);

    float h = 0.0f;
    if (valid) {
        const float sg     = sel3(s, s0, s1, s2v);
        const float inv_rc = __builtin_amdgcn_rcpf(r - c);   // negative
        const float l2     = log2f(sg * __builtin_amdgcn_rcpf(r));
        const float e2     = sel3(s, a0, a1, a2)
                           * (sel3(s, b0, b1, b2) * exp2f(sel3(s, p0, p1, p2) * l2)
                              - exp2f(sel3(s, q0, q1, q2) * l2))
                           * expf(sg * inv_rc);
        acc += 0.5f * e2;
        h = sel3(s, g0, g1, g2) * inv_rc;                    // gamma/(r - c)
    }

    // triplet participation: ej == 1-ei (=> ei!=ej & ej==ek automatic) and rij<cij
    const bool participate = valid && (ej != ei);
    const unsigned long long ballot   = __ballot(participate);
    const unsigned long long halfmask = side ? 0xFFFFFFFF00000000ull : 0x00000000FFFFFFFFull;
    const int m = __popcll(ballot & halfmask);
    if (participate) {
        const int slot = __popcll(ballot & halfmask & ((1ull << lane) - 1ull));
        cpos[wave][side][slot] = make_float4(dx, dy, dz, r);
        chh [wave][side][slot] = h;
    }
    // wave-private LDS, wave-lockstep: no barrier needed

    // ---- triplet term over compacted pairs (usually <= 1 iteration) ----
    const float lam_e = ei ? lam1 : lam0;
    const float cb_e  = ei ? cb1v : cb0v;
    const float cjk_e = ei ? cjk1 : cjk0;
    const float cjk2  = cjk_e * cjk_e;
    const int npairs  = (m * (m - 1)) >> 1;

    for (int t = hl; t < npairs; t += 32) {
        int kk = (int)(0.5f * (1.0f + __builtin_amdgcn_sqrtf(8.0f * (float)t + 1.0f)));
        if (kk*(kk-1)/2 > t)          --kk;
        else if ((kk+1)*kk/2 <= t)    ++kk;
        const int jj = t - ((kk*(kk-1)) >> 1);

        const float4 pj = cpos[wave][side][jj];
        const float4 pk = cpos[wave][side][kk];
        const float dxv  = pk.x - pj.x;
        const float dyv  = pk.y - pj.y;
        const float dzv  = pk.z - pj.z;
        const float rjk2 = dxv*dxv + dyv*dyv + dzv*dzv;
        if (rjk2 < cjk2) {
            const float rj   = pj.w;
            const float rk   = pk.w;
            const float cosb = (rj*rj + rk*rk - rjk2)
                             * 0.5f * __builtin_amdgcn_rcpf(rj * rk);
            const float dcb  = cosb - cb_e;
            acc += lam_e * expf(chh[wave][side][jj] + chh[wave][side][kk]) * dcb * dcb;
        }
    }

    // ---- wave reduce (64 lanes); one partial per wave, no block barrier ----
    #pragma unroll
    for (int off = 32; off > 0; off >>= 1)
        acc += __shfl_xor(acc, off, 64);
    if (lane == 0)
        wave_sums[(blockIdx.x << 2) + wave] = acc;
}

__global__ __launch_bounds__(256) void sw_reduce_kernel(
    const float* __restrict__ in, float* __restrict__ out)
{
    __shared__ float wsum[4];
    const float4* v = (const float4*)in;          // NWAVESUM/4 = 2048 float4
    float acc = 0.0f;
    #pragma unroll
    for (int i = 0; i < (NWAVESUM / 4) / 256; ++i) {
        const float4 x = v[threadIdx.x + i * 256];
        acc += (x.x + x.y) + (x.z + x.w);
    }
    #pragma unroll
    for (int off = 32; off > 0; off >>= 1)
        acc += __shfl_xor(acc, off, 64);
    if ((threadIdx.x & 63) == 0) wsum[threadIdx.x >> 6] = acc;
    __syncthreads();
    if (threadIdx.x == 0) out[0] = wsum[0] + wsum[1] + wsum[2] + wsum[3];
}

extern "C" void kernel_launch(void* const* d_in, const int* in_sizes, int n_in,
                              void* d_out, int out_size, void* d_ws, size_t ws_size,
                              hipStream_t stream)
{
    const float* coords  = (const float*)d_in[0];
    const float* A_      = (const float*)d_in[1];
    const float* B_      = (const float*)d_in[2];
    const float* p_      = (const float*)d_in[3];
    const float* q_      = (const float*)d_in[4];
    const float* sigma_  = (const float*)d_in[5];
    const float* gamma_  = (const float*)d_in[6];
    const float* cutoff_ = (const float*)d_in[7];
    const float* lam_    = (const float*)d_in[8];
    const float* cb0_    = (const float*)d_in[9];
    const float* cjk_    = (const float*)d_in[10];
    const int*   elements= (const int*)d_in[11];
    const int*   nl      = (const int*)d_in[12];

    float* out   = (float*)d_out;
    float* wsums = (float*)d_ws;               // 8192 floats scratch

    sw_energy_kernel<<<NBLK, 256, 0, stream>>>(
        coords, A_, B_, p_, q_, sigma_, gamma_, cutoff_,
        lam_, cb0_, cjk_, elements, nl, wsums);
    sw_reduce_kernel<<<1, 256, 0, stream>>>(wsums, out);
}

// Round 6
// 11.605 us; speedup vs baseline: 2.3058x; 1.0169x over previous
//
#include <hip/hip_runtime.h>
#include <cmath>

#define NATOMS 16384
#define MNBR   32
#define ROW    33      // center + 32 neighbors
#define NBLK   2048    // 8 atoms/block: 4 waves x 2 half-waves
#define NWAVESUM (NBLK * 4)
#define LOG2E  1.4426950408889634f

__device__ __forceinline__ float sel3(int s, float v0, float v1, float v2) {
    float r = (s == 0) ? v0 : v1;
    return (s == 2) ? v2 : r;
}

__global__ __launch_bounds__(256, 8) void sw_energy_kernel(
    const float* __restrict__ coords,
    const float* __restrict__ A_,    const float* __restrict__ B_,
    const float* __restrict__ p_,    const float* __restrict__ q_,
    const float* __restrict__ sigma_,const float* __restrict__ gamma_,
    const float* __restrict__ cutoff_,const float* __restrict__ lam_,
    const float* __restrict__ cb0_,  const float* __restrict__ cjk_,
    const int*   __restrict__ elements,
    const int*   __restrict__ nl,
    float* __restrict__ wave_sums)
{
    // wave-private compacted triplet candidates: [wave][side][slot]
    __shared__ float4 cpos[4][2][32];   // {dx, dy, dz, r}
    __shared__ float  chh [4][2][32];   // gamma/(r-c)

    const int tid  = threadIdx.x;
    const int wave = tid >> 6;
    const int lane = tid & 63;
    const int side = lane >> 5;
    const int hl   = lane & 31;

    // uniform params -> scalar loads, no LDS, no barrier
    const float a0 = A_[0],     a1 = A_[1],     a2 = A_[2];
    const float b0 = B_[0],     b1 = B_[1],     b2 = B_[2];
    const float p0 = p_[0],     p1 = p_[1],     p2 = p_[2];
    const float q0 = q_[0],     q1 = q_[1],     q2 = q_[2];
    const float s0 = sigma_[0], s1 = sigma_[1], s2v = sigma_[2];
    const float g0 = gamma_[0], g1 = gamma_[1], g2 = gamma_[2];
    const float c0 = cutoff_[0],c1 = cutoff_[1],c2 = cutoff_[2];
    const float lam0 = lam_[0], lam1 = lam_[1];
    const float cb0v = cb0_[0], cb1v = cb0_[1];
    const float cjk0 = cjk_[0], cjk1 = cjk_[1];

    // wave-uniform fast-path check (runtime inputs are p=5, q=0)
    const bool fastpq = (p0 == 5.0f) & (p1 == 5.0f) & (p2 == 5.0f)
                      & (q0 == 0.0f) & (q1 == 0.0f) & (q2 == 0.0f);

    const int atom = (blockIdx.x << 3) + wave * 2 + side;   // grid exact
    const int base = atom * ROW;

    const int   ei  = elements[base];
    const int   ci  = nl[base];
    const float xix = coords[3*ci+0];
    const float xiy = coords[3*ci+1];
    const float xiz = coords[3*ci+2];

    float acc = 0.0f;

    // ---- pair term + triplet-candidate compaction (all 64 lanes busy) ----
    const int   j  = nl[base + 1 + hl];
    const int   ej = elements[base + 1 + hl];
    const float dx = coords[3*j+0] - xix;
    const float dy = coords[3*j+1] - xiy;
    const float dz = coords[3*j+2] - xiz;
    const float d2 = dx*dx + dy*dy + dz*dz;
    const float inv_r = __builtin_amdgcn_rsqf(d2);           // 1/r
    const float r     = d2 * inv_r;                          // r
    const int   s  = ei + ej;
    const float c  = sel3(s, c0, c1, c2);
    const bool  valid = (r < c);

    float h = 0.0f;
    if (valid) {
        const float sg     = sel3(s, s0, s1, s2v);
        const float inv_rc = __builtin_amdgcn_rcpf(r - c);   // negative
        const float sr     = sg * inv_r;
        float poly;
        if (fastpq) {
            const float sr2 = sr * sr;
            poly = sel3(s, b0, b1, b2) * (sr2 * sr2 * sr) - 1.0f;
        } else {
            const float l2 = log2f(sr);
            poly = sel3(s, b0, b1, b2) * exp2f(sel3(s, p0, p1, p2) * l2)
                 - exp2f(sel3(s, q0, q1, q2) * l2);
        }
        const float e2 = sel3(s, a0, a1, a2) * poly
                       * __builtin_amdgcn_exp2f(LOG2E * sg * inv_rc);
        acc += 0.5f * e2;
        h = sel3(s, g0, g1, g2) * inv_rc;                    // gamma/(r - c)
    }

    // triplet participation: ej == 1-ei (=> ei!=ej & ej==ek automatic) and rij<cij
    const bool participate = valid && (ej != ei);
    const unsigned long long ballot   = __ballot(participate);
    const unsigned long long halfmask = side ? 0xFFFFFFFF00000000ull : 0x00000000FFFFFFFFull;
    const int m = __popcll(ballot & halfmask);
    if (participate) {
        const int slot = __popcll(ballot & halfmask & ((1ull << lane) - 1ull));
        cpos[wave][side][slot] = make_float4(dx, dy, dz, r);
        chh [wave][side][slot] = h;
    }
    // wave-private LDS, wave-lockstep: no barrier needed

    // ---- triplet term over compacted pairs (usually <= 1 iteration) ----
    const float lam_e = ei ? lam1 : lam0;
    const float cb_e  = ei ? cb1v : cb0v;
    const float cjk_e = ei ? cjk1 : cjk0;
    const float cjk2  = cjk_e * cjk_e;
    const int npairs  = (m * (m - 1)) >> 1;

    for (int t = hl; t < npairs; t += 32) {
        int kk = (int)(0.5f * (1.0f + __builtin_amdgcn_sqrtf(8.0f * (float)t + 1.0f)));
        if (kk*(kk-1)/2 > t)          --kk;
        else if ((kk+1)*kk/2 <= t)    ++kk;
        const int jj = t - ((kk*(kk-1)) >> 1);

        const float4 pj = cpos[wave][side][jj];
        const float4 pk = cpos[wave][side][kk];
        const float dxv  = pk.x - pj.x;
        const float dyv  = pk.y - pj.y;
        const float dzv  = pk.z - pj.z;
        const float rjk2 = dxv*dxv + dyv*dyv + dzv*dzv;
        if (rjk2 < cjk2) {
            const float rj   = pj.w;
            const float rk   = pk.w;
            const float cosb = (rj*rj + rk*rk - rjk2)
                             * 0.5f * __builtin_amdgcn_rcpf(rj * rk);
            const float dcb  = cosb - cb_e;
            acc += lam_e * dcb * dcb
                 * __builtin_amdgcn_exp2f(LOG2E * (chh[wave][side][jj] + chh[wave][side][kk]));
        }
    }

    // ---- wave reduce (64 lanes); one partial per wave, no block barrier ----
    #pragma unroll
    for (int off = 32; off > 0; off >>= 1)
        acc += __shfl_xor(acc, off, 64);
    if (lane == 0)
        wave_sums[(blockIdx.x << 2) + wave] = acc;
}

__global__ __launch_bounds__(256) void sw_reduce_kernel(
    const float* __restrict__ in, float* __restrict__ out)
{
    __shared__ float wsum[4];
    const float4* v = (const float4*)in;          // NWAVESUM/4 = 2048 float4
    float acc = 0.0f;
    #pragma unroll
    for (int i = 0; i < (NWAVESUM / 4) / 256; ++i) {
        const float4 x = v[threadIdx.x + i * 256];
        acc += (x.x + x.y) + (x.z + x.w);
    }
    #pragma unroll
    for (int off = 32; off > 0; off >>= 1)
        acc += __shfl_xor(acc, off, 64);
    if ((threadIdx.x & 63) == 0) wsum[threadIdx.x >> 6] = acc;
    __syncthreads();
    if (threadIdx.x == 0) out[0] = wsum[0] + wsum[1] + wsum[2] + wsum[3];
}

extern "C" void kernel_launch(void* const* d_in, const int* in_sizes, int n_in,
                              void* d_out, int out_size, void* d_ws, size_t ws_size,
                              hipStream_t stream)
{
    const float* coords  = (const float*)d_in[0];
    const float* A_      = (const float*)d_in[1];
    const float* B_      = (const float*)d_in[2];
    const float* p_      = (const float*)d_in[3];
    const float* q_      = (const float*)d_in[4];
    const float* sigma_  = (const float*)d_in[5];
    const float* gamma_  = (const float*)d_in[6];
    const float* cutoff_ = (const float*)d_in[7];
    const float* lam_    = (const float*)d_in[8];
    const float* cb0_    = (const float*)d_in[9];
    const float* cjk_    = (const float*)d_in[10];
    const int*   elements= (const int*)d_in[11];
    const int*   nl      = (const int*)d_in[12];

    float* out   = (float*)d_out;
    float* wsums = (float*)d_ws;               // 8192 floats scratch

    sw_energy_kernel<<<NBLK, 256, 0, stream>>>(
        coords, A_, B_, p_, q_, sigma_, gamma_, cutoff_,
        lam_, cb0_, cjk_, elements, nl, wsums);
    sw_reduce_kernel<<<1, 256, 0, stream>>>(wsums, out);
}

// Round 7
// 11.348 us; speedup vs baseline: 2.3579x; 1.0226x over previous
//
#include <hip/hip_runtime.h>
#include <cmath>

#define NATOMS 16384
#define MNBR   32
#define ROW    33      // center + 32 neighbors
#define NBLK   2048    // 8 atoms/block: 4 waves x 2 half-waves
#define LOG2E  1.4426950408889634f

// 16-byte vector with 4-byte alignment guarantee (coords rows are only dword-aligned)
typedef float f4v __attribute__((ext_vector_type(4), aligned(4)));

__device__ __forceinline__ float sel3(int s, float v0, float v1, float v2) {
    float r = (s == 0) ? v0 : v1;
    return (s == 2) ? v2 : r;
}

// load coords[3j .. 3j+2] with ONE dwordx4; safe at the array end
__device__ __forceinline__ void load_xyz(const float* __restrict__ coords, int j,
                                         float& x, float& y, float& z) {
    const bool last = (j == NATOMS - 1);
    const int  off  = 3 * j - (last ? 1 : 0);
    const f4v  v    = *reinterpret_cast<const f4v*>(coords + off);
    x = last ? v.y : v.x;
    y = last ? v.z : v.y;
    z = last ? v.w : v.z;
}

__global__ __launch_bounds__(256, 8) void sw_energy_kernel(
    const float* __restrict__ coords,
    const float* __restrict__ A_,    const float* __restrict__ B_,
    const float* __restrict__ p_,    const float* __restrict__ q_,
    const float* __restrict__ sigma_,const float* __restrict__ gamma_,
    const float* __restrict__ cutoff_,const float* __restrict__ lam_,
    const float* __restrict__ cb0_,  const float* __restrict__ cjk_,
    const int*   __restrict__ elements,
    const int*   __restrict__ nl,
    float* __restrict__ block_sums)
{
    // wave-private compacted triplet candidates: [wave][side][slot]
    __shared__ float4 cpos[4][2][32];   // {dx, dy, dz, r}
    __shared__ float  chh [4][2][32];   // gamma/(r-c)
    __shared__ float  wsum[4];

    const int tid  = threadIdx.x;
    const int wave = tid >> 6;
    const int lane = tid & 63;
    const int side = lane >> 5;
    const int hl   = lane & 31;

    // uniform params -> scalar loads, no LDS, no barrier
    const float a0 = A_[0],     a1 = A_[1],     a2 = A_[2];
    const float b0 = B_[0],     b1 = B_[1],     b2 = B_[2];
    const float p0 = p_[0],     p1 = p_[1],     p2 = p_[2];
    const float q0 = q_[0],     q1 = q_[1],     q2 = q_[2];
    const float s0 = sigma_[0], s1 = sigma_[1], s2v = sigma_[2];
    const float g0 = gamma_[0], g1 = gamma_[1], g2 = gamma_[2];
    const float c0 = cutoff_[0],c1 = cutoff_[1],c2 = cutoff_[2];
    const float lam0 = lam_[0], lam1 = lam_[1];
    const float cb0v = cb0_[0], cb1v = cb0_[1];
    const float cjk0 = cjk_[0], cjk1 = cjk_[1];

    // wave-uniform fast-path check (runtime inputs are p=5, q=0)
    const bool fastpq = (p0 == 5.0f) & (p1 == 5.0f) & (p2 == 5.0f)
                      & (q0 == 0.0f) & (q1 == 0.0f) & (q2 == 0.0f);

    const int atom = (blockIdx.x << 3) + wave * 2 + side;   // grid exact
    const int base = atom * ROW;

    const int ei = elements[base];
    const int ci = nl[base];
    float xix, xiy, xiz;
    load_xyz(coords, ci, xix, xiy, xiz);

    float acc = 0.0f;

    // ---- pair term + triplet-candidate compaction (all 64 lanes busy) ----
    const int j  = nl[base + 1 + hl];
    const int ej = elements[base + 1 + hl];
    float cjx, cjy, cjz;
    load_xyz(coords, j, cjx, cjy, cjz);
    const float dx = cjx - xix;
    const float dy = cjy - xiy;
    const float dz = cjz - xiz;
    const float d2 = dx*dx + dy*dy + dz*dz;
    const float inv_r = __builtin_amdgcn_rsqf(d2);           // 1/r
    const float r     = d2 * inv_r;                          // r
    const int   s  = ei + ej;
    const float c  = sel3(s, c0, c1, c2);
    const bool  valid = (r < c);

    float h = 0.0f;
    if (valid) {
        const float sg     = sel3(s, s0, s1, s2v);
        const float inv_rc = __builtin_amdgcn_rcpf(r - c);   // negative
        const float sr     = sg * inv_r;
        float poly;
        if (fastpq) {
            const float sr2 = sr * sr;
            poly = sel3(s, b0, b1, b2) * (sr2 * sr2 * sr) - 1.0f;
        } else {
            const float l2 = log2f(sr);
            poly = sel3(s, b0, b1, b2) * exp2f(sel3(s, p0, p1, p2) * l2)
                 - exp2f(sel3(s, q0, q1, q2) * l2);
        }
        const float e2 = sel3(s, a0, a1, a2) * poly
                       * __builtin_amdgcn_exp2f(LOG2E * sg * inv_rc);
        acc += 0.5f * e2;
        h = sel3(s, g0, g1, g2) * inv_rc;                    // gamma/(r - c)
    }

    // triplet participation: ej == 1-ei (=> ei!=ej & ej==ek automatic) and rij<cij
    const bool participate = valid && (ej != ei);
    const unsigned long long ballot   = __ballot(participate);
    const unsigned long long halfmask = side ? 0xFFFFFFFF00000000ull : 0x00000000FFFFFFFFull;
    const int m = __popcll(ballot & halfmask);
    if (participate) {
        const int slot = __popcll(ballot & halfmask & ((1ull << lane) - 1ull));
        cpos[wave][side][slot] = make_float4(dx, dy, dz, r);
        chh [wave][side][slot] = h;
    }
    // wave-private LDS, wave-lockstep: no barrier needed

    // ---- triplet term over compacted pairs (usually <= 1 iteration) ----
    const float lam_e = ei ? lam1 : lam0;
    const float cb_e  = ei ? cb1v : cb0v;
    const float cjk_e = ei ? cjk1 : cjk0;
    const float cjk2  = cjk_e * cjk_e;
    const int npairs  = (m * (m - 1)) >> 1;

    for (int t = hl; t < npairs; t += 32) {
        int kk = (int)(0.5f * (1.0f + __builtin_amdgcn_sqrtf(8.0f * (float)t + 1.0f)));
        if (kk*(kk-1)/2 > t)          --kk;
        else if ((kk+1)*kk/2 <= t)    ++kk;
        const int jj = t - ((kk*(kk-1)) >> 1);

        const float4 pj = cpos[wave][side][jj];
        const float4 pk = cpos[wave][side][kk];
        const float dxv  = pk.x - pj.x;
        const float dyv  = pk.y - pj.y;
        const float dzv  = pk.z - pj.z;
        const float rjk2 = dxv*dxv + dyv*dyv + dzv*dzv;
        if (rjk2 < cjk2) {
            const float rj   = pj.w;
            const float rk   = pk.w;
            const float cosb = (rj*rj + rk*rk - rjk2)
                             * 0.5f * __builtin_amdgcn_rcpf(rj * rk);
            const float dcb  = cosb - cb_e;
            acc += lam_e * dcb * dcb
                 * __builtin_amdgcn_exp2f(LOG2E * (chh[wave][side][jj] + chh[wave][side][kk]));
        }
    }

    // ---- wave reduce, then block sum (one float per block) ----
    #pragma unroll
    for (int off = 32; off > 0; off >>= 1)
        acc += __shfl_xor(acc, off, 64);
    if (lane == 0) wsum[wave] = acc;
    __syncthreads();
    if (tid == 0)
        block_sums[blockIdx.x] = (wsum[0] + wsum[1]) + (wsum[2] + wsum[3]);
}

__global__ __launch_bounds__(512) void sw_reduce_kernel(
    const float* __restrict__ in, float* __restrict__ out)
{
    __shared__ float wsum[8];
    // 2048 floats = 512 float4, exactly one load per thread (depth 1)
    const float4 x = ((const float4*)in)[threadIdx.x];
    float acc = (x.x + x.y) + (x.z + x.w);
    #pragma unroll
    for (int off = 32; off > 0; off >>= 1)
        acc += __shfl_xor(acc, off, 64);
    if ((threadIdx.x & 63) == 0) wsum[threadIdx.x >> 6] = acc;
    __syncthreads();
    if (threadIdx.x == 0) {
        float t = 0.0f;
        #pragma unroll
        for (int i = 0; i < 8; ++i) t += wsum[i];
        out[0] = t;
    }
}

extern "C" void kernel_launch(void* const* d_in, const int* in_sizes, int n_in,
                              void* d_out, int out_size, void* d_ws, size_t ws_size,
                              hipStream_t stream)
{
    const float* coords  = (const float*)d_in[0];
    const float* A_      = (const float*)d_in[1];
    const float* B_      = (const float*)d_in[2];
    const float* p_      = (const float*)d_in[3];
    const float* q_      = (const float*)d_in[4];
    const float* sigma_  = (const float*)d_in[5];
    const float* gamma_  = (const float*)d_in[6];
    const float* cutoff_ = (const float*)d_in[7];
    const float* lam_    = (const float*)d_in[8];
    const float* cb0_    = (const float*)d_in[9];
    const float* cjk_    = (const float*)d_in[10];
    const int*   elements= (const int*)d_in[11];
    const int*   nl      = (const int*)d_in[12];

    float* out   = (float*)d_out;
    float* bsums = (float*)d_ws;               // 2048 floats scratch

    sw_energy_kernel<<<NBLK, 256, 0, stream>>>(
        coords, A_, B_, p_, q_, sigma_, gamma_, cutoff_,
        lam_, cb0_, cjk_, elements, nl, bsums);
    sw_reduce_kernel<<<1, 512, 0, stream>>>(bsums, out);
}